// Round 3
// baseline (1693.468 us; speedup 1.0000x reference)
//
#include <hip/hip_runtime.h>
#include <math.h>

typedef unsigned short u16;
typedef __bf16 bf16x8 __attribute__((ext_vector_type(8)));
typedef float f32x4 __attribute__((ext_vector_type(4)));

static __device__ __forceinline__ float sigf(float x){ return 1.0f/(1.0f+expf(-x)); }
static __device__ __forceinline__ u16 f2bf(float f){
    unsigned u = __builtin_bit_cast(unsigned, f);
    unsigned r = u + 0x7FFFu + ((u >> 16) & 1u);
    return (u16)(r >> 16);
}
static __device__ __forceinline__ float b2f(u16 s){
    unsigned u = ((unsigned)s) << 16;
    return __builtin_bit_cast(float, u);
}

// ---------------------------------------------------------------------------
// Weight prep
// ---------------------------------------------------------------------------
// Wt[n][k] = bf16(W[k][n]), zero-padded to Kpad (transpose)
__global__ void prep_w(const float* __restrict__ W, u16* __restrict__ Wt,
                       int K, int N, int Kpad)
{
    int idx = blockIdx.x * 256 + threadIdx.x;
    if (idx >= N * Kpad) return;
    int n = idx / Kpad, k = idx - n * Kpad;
    Wt[idx] = (k < K) ? f2bf(W[(long)k * N + n]) : (u16)0;
}
// straight f32 -> bf16 convert (already [N][K])
__global__ void prep_cvt(const float* __restrict__ W, u16* __restrict__ Wt, int total)
{
    int idx = blockIdx.x * 256 + threadIdx.x;
    if (idx < total) Wt[idx] = f2bf(W[idx]);
}
__global__ void prep_bias(const float* __restrict__ b_ih, const float* __restrict__ b_hh,
                          float* __restrict__ bsum)
{
    int idx = blockIdx.x * 256 + threadIdx.x;
    if (idx < 1024) bsum[idx] = b_ih[idx] + b_hh[idx];
}

// ---------------------------------------------------------------------------
// Generic MFMA GEMM: C[M x N] = act(A @ Bt^T + bias) * rowscale
//   A: f32 (converted during staging) or bf16, row-major, lda
//   Bt: bf16 [N][Kpad] pre-transposed weights
//   tile 128 x BN, BK=32, 256 threads, mfma_f32_16x16x32_bf16
//   permA: logical row r -> input row (r&1023)*63 + (r>>10)
// ---------------------------------------------------------------------------
template<bool AF32, int BN>
__launch_bounds__(256)
__global__ void gemm_bf16(const void* __restrict__ Aptr, const u16* __restrict__ Bt,
                          void* __restrict__ Cout, const float* __restrict__ bias,
                          const float* __restrict__ rowscale,
                          int Kreal, int Kpad, int lda, int ldc,
                          int permA, int act, int outBF16)
{
    constexpr int BM = 128, LDT = 40;
    constexpr int WM = (BN >= 128) ? 2 : 4;        // waves along M
    constexpr int WN = 4 / WM;                     // waves along N
    constexpr int MI = BM / WM / 16;
    constexpr int NI = BN / WN / 16;
    __shared__ u16 As[BM * LDT];
    __shared__ u16 Bs[BN * LDT];

    const int tid = threadIdx.x;
    const int lane = tid & 63, wv = tid >> 6;
    const int r0 = blockIdx.x * BM, c0 = blockIdx.y * BN;
    const int wr = (wv % WM) * (BM / WM);
    const int wc = (wv / WM) * (BN / WN);
    const int l15 = lane & 15, q8 = (lane >> 4) * 8;

    f32x4 acc[MI][NI];
#pragma unroll
    for (int i = 0; i < MI; i++)
#pragma unroll
        for (int j = 0; j < NI; j++) acc[i][j] = (f32x4){0.f, 0.f, 0.f, 0.f};

    for (int kt = 0; kt < Kpad; kt += 32) {
        if (AF32) {
            const float* Ag = (const float*)Aptr;
#pragma unroll
            for (int p = 0; p < 4; p++) {
                int v = tid + p * 256;
                int row = v >> 3, kc = (v & 7) * 4;
                long ar = r0 + row;
                long arow = permA ? ((ar & 1023) * 63 + (ar >> 10)) : ar;
                int k = kt + kc;
                float4 val;
                if (k + 4 <= Kreal) {
                    val = *(const float4*)(Ag + arow * (long)lda + k);
                } else {
                    val.x = (k + 0 < Kreal) ? Ag[arow * (long)lda + k + 0] : 0.f;
                    val.y = (k + 1 < Kreal) ? Ag[arow * (long)lda + k + 1] : 0.f;
                    val.z = (k + 2 < Kreal) ? Ag[arow * (long)lda + k + 2] : 0.f;
                    val.w = (k + 3 < Kreal) ? Ag[arow * (long)lda + k + 3] : 0.f;
                }
                ushort4 o; o.x = f2bf(val.x); o.y = f2bf(val.y); o.z = f2bf(val.z); o.w = f2bf(val.w);
                *(ushort4*)&As[row * LDT + kc] = o;
            }
        } else {
            const u16* Ag = (const u16*)Aptr;
#pragma unroll
            for (int p = 0; p < 2; p++) {
                int v = tid + p * 256;
                int row = v >> 2, kc = (v & 3) * 8;
                long ar = r0 + row;
                *(int4*)&As[row * LDT + kc] = *(const int4*)(Ag + ar * (long)lda + kt + kc);
            }
        }
        constexpr int BCH = BN * 4 / 256;
#pragma unroll
        for (int p = 0; p < BCH; p++) {
            int v = tid + p * 256;
            int row = v >> 2, kc = (v & 3) * 8;
            *(int4*)&Bs[row * LDT + kc] = *(const int4*)(Bt + (long)(c0 + row) * Kpad + kt + kc);
        }
        __syncthreads();

        bf16x8 af[MI], bfr[NI];
#pragma unroll
        for (int mi = 0; mi < MI; mi++)
            af[mi] = *reinterpret_cast<const bf16x8*>(&As[(wr + mi * 16 + l15) * LDT + q8]);
#pragma unroll
        for (int ni = 0; ni < NI; ni++)
            bfr[ni] = *reinterpret_cast<const bf16x8*>(&Bs[(wc + ni * 16 + l15) * LDT + q8]);
#pragma unroll
        for (int mi = 0; mi < MI; mi++)
#pragma unroll
            for (int ni = 0; ni < NI; ni++)
                acc[mi][ni] = __builtin_amdgcn_mfma_f32_16x16x32_bf16(af[mi], bfr[ni], acc[mi][ni], 0, 0, 0);
        __syncthreads();
    }

#pragma unroll
    for (int mi = 0; mi < MI; mi++) {
#pragma unroll
        for (int ni = 0; ni < NI; ni++) {
#pragma unroll
            for (int r = 0; r < 4; r++) {
                int row = r0 + wr + mi * 16 + (lane >> 4) * 4 + r;
                int col = c0 + wc + ni * 16 + l15;
                float v = acc[mi][ni][r];
                if (bias) v += bias[col];
                if (act == 1) v = tanhf(v);
                if (rowscale) v *= rowscale[(row & 1023) * 63 + (row >> 10)];
                if (outBF16) ((u16*)Cout)[(long)row * ldc + col] = f2bf(v);
                else         ((float*)Cout)[(long)row * ldc + col] = v;
            }
        }
    }
}

// ---------------------------------------------------------------------------
// Level-0 LSTM: h0 = 0, c0 = 0 -> pointwise on precomputed x-gates.
// gates layout per row: [i(256) | f(256) | g(256) | o(256)], bf16, biases folded.
// ---------------------------------------------------------------------------
__launch_bounds__(256)
__global__ void lstm0(const u16* __restrict__ xg, u16* __restrict__ Hbuf,
                      float* __restrict__ Cbuf)
{
    int idx = blockIdx.x * 256 + threadIdx.x;   // 32768*64 = 2,097,152
    int row = idx >> 6;
    int c4 = (idx & 63) * 4;
    const u16* g = xg + (long)row * 1024;
    ushort4 i4 = *(const ushort4*)(g + c4);
    ushort4 g4 = *(const ushort4*)(g + 512 + c4);
    ushort4 o4 = *(const ushort4*)(g + 768 + c4);
    float cv[4], hv[4];
    u16 iv[4] = {i4.x, i4.y, i4.z, i4.w};
    u16 gv[4] = {g4.x, g4.y, g4.z, g4.w};
    u16 ov[4] = {o4.x, o4.y, o4.z, o4.w};
#pragma unroll
    for (int j = 0; j < 4; j++) {
        cv[j] = sigf(b2f(iv[j])) * tanhf(b2f(gv[j]));
        hv[j] = sigf(b2f(ov[j])) * tanhf(cv[j]);
    }
    long ob = (long)row * 256 + c4;
    *(float4*)(Cbuf + ob) = make_float4(cv[0], cv[1], cv[2], cv[3]);
    ushort4 h4; h4.x = f2bf(hv[0]); h4.y = f2bf(hv[1]); h4.z = f2bf(hv[2]); h4.w = f2bf(hv[3]);
    *(ushort4*)(Hbuf + ob) = h4;
}

// ---------------------------------------------------------------------------
// Levels 1..5: gates = xg + h0 @ W_hh^T, then LSTM combine.
// Block: 128 rows x (4 gates x 64 cells). K = 256, BK = 32.
// ---------------------------------------------------------------------------
__launch_bounds__(256)
__global__ void gates_h(const u16* __restrict__ h0, const u16* __restrict__ Wt_hh,
                        const u16* __restrict__ xg,
                        const float* __restrict__ Cprev,
                        u16* __restrict__ Hbuf, float* __restrict__ Cbuf,
                        int offCur, int offPrev)
{
    constexpr int LDT = 40, LDG = 264;
    __shared__ u16 smem[128 * LDG];            // 67.6 KB; Gs aliases As/Bs
    u16* As = smem;                             // 128 x LDT
    u16* Bs = smem + 128 * LDT;                 // 256 x LDT
    u16* Gs = smem;                             // 128 x LDG (gate tiles)

    const int tid = threadIdx.x;
    const int lane = tid & 63, wv = tid >> 6;
    const int r0 = blockIdx.x * 128;
    const int cb = blockIdx.y * 64;             // cell base
    const int wr = (wv & 1) * 64, wc = (wv >> 1) * 128;
    const int l15 = lane & 15, q8 = (lane >> 4) * 8;

    f32x4 acc[4][8];
#pragma unroll
    for (int i = 0; i < 4; i++)
#pragma unroll
        for (int j = 0; j < 8; j++) acc[i][j] = (f32x4){0.f, 0.f, 0.f, 0.f};

    for (int kt = 0; kt < 256; kt += 32) {
#pragma unroll
        for (int p = 0; p < 2; p++) {
            int v = tid + p * 256;
            int row = v >> 2, kc = (v & 3) * 8;
            *(int4*)&As[row * LDT + kc] = *(const int4*)(h0 + (long)(r0 + row) * 256 + kt + kc);
        }
#pragma unroll
        for (int p = 0; p < 4; p++) {
            int v = tid + p * 256;
            int row = v >> 2, kc = (v & 3) * 8;
            long brow = (long)((row >> 6) * 256 + cb + (row & 63));
            *(int4*)&Bs[row * LDT + kc] = *(const int4*)(Wt_hh + brow * 256 + kt + kc);
        }
        __syncthreads();

        bf16x8 af[4], bfr[8];
#pragma unroll
        for (int mi = 0; mi < 4; mi++)
            af[mi] = *reinterpret_cast<const bf16x8*>(&As[(wr + mi * 16 + l15) * LDT + q8]);
#pragma unroll
        for (int ni = 0; ni < 8; ni++)
            bfr[ni] = *reinterpret_cast<const bf16x8*>(&Bs[(wc + ni * 16 + l15) * LDT + q8]);
#pragma unroll
        for (int mi = 0; mi < 4; mi++)
#pragma unroll
            for (int ni = 0; ni < 8; ni++)
                acc[mi][ni] = __builtin_amdgcn_mfma_f32_16x16x32_bf16(af[mi], bfr[ni], acc[mi][ni], 0, 0, 0);
        __syncthreads();
    }

    // dump gate tiles (+ xg with folded biases) to LDS
#pragma unroll
    for (int mi = 0; mi < 4; mi++)
#pragma unroll
        for (int ni = 0; ni < 8; ni++)
#pragma unroll
            for (int r = 0; r < 4; r++) {
                int lr = wr + mi * 16 + (lane >> 4) * 4 + r;
                int lc = wc + ni * 16 + l15;
                int gc = (lc >> 6) * 256 + cb + (lc & 63);
                long xrow = (long)offCur * 1024 + r0 + lr;
                float v = acc[mi][ni][r] + b2f(xg[xrow * 1024 + gc]);
                Gs[lr * LDG + lc] = f2bf(v);
            }
    __syncthreads();

    // LSTM combine: 32 (row, cell) pairs per thread
#pragma unroll
    for (int i = 0; i < 32; i++) {
        int idx = i * 256 + tid;
        int row = idx >> 6, cell = idx & 63;
        float iv = b2f(Gs[row * LDG + cell]);
        float fv = b2f(Gs[row * LDG + 64 + cell]);
        float gv = b2f(Gs[row * LDG + 128 + cell]);
        float ov = b2f(Gs[row * LDG + 192 + cell]);
        int rloc = r0 + row;
        int nd = rloc >> 10, bb = rloc & 1023;
        int gcol = cb + cell;
        long ch = ((long)(offPrev + nd * 2) * 1024 + bb) * 256 + gcol;
        float c0v = 0.5f * (Cprev[ch] + Cprev[ch + 262144]);
        float cv = sigf(fv) * c0v + sigf(iv) * tanhf(gv);
        float hv = sigf(ov) * tanhf(cv);
        long orow = ((long)offCur * 1024 + rloc) * 256 + gcol;
        Cbuf[orow] = cv;
        Hbuf[orow] = f2bf(hv);
    }
}

// ---------------------------------------------------------------------------
// Attention logits: one wave per descendant row (global node g < off).
// ---------------------------------------------------------------------------
__launch_bounds__(256)
__global__ void attn_logits(const float* __restrict__ E, const float* __restrict__ xextall,
                            const float* __restrict__ W_a, float* __restrict__ Lbuf,
                            int level, int rows, int m, int off)
{
    const int wv = threadIdx.x >> 6, ln = threadIdx.x & 63;
    const long dr = (long)blockIdx.x * 4 + wv;
    if (dr >= rows) return;
    const int g = (int)(dr >> 10), bb = (int)(dr & 1023);
    int lp, node;
    if      (g < 32) { lp = 0; node = g;      }
    else if (g < 48) { lp = 1; node = g - 32; }
    else if (g < 56) { lp = 2; node = g - 48; }
    else if (g < 60) { lp = 3; node = g - 56; }
    else             { lp = 4; node = g - 60; }
    const int shift  = level - lp;
    const int i      = node >> shift;
    const int within = node & ((1 << shift) - 1);
    const int d      = ((2 << level) - (2 << shift)) + within;

    float e = E[dr * 64 + ln] + xextall[((long)(off + i) * 1024 + bb) * 64 + ln];
    float v = tanhf(e) * W_a[ln];
#pragma unroll
    for (int s = 32; s; s >>= 1) v += __shfl_xor(v, s);
    if (ln == 0) Lbuf[((long)(i * m + d)) * 1024 + bb] = v;
}

// ---------------------------------------------------------------------------
// Softmax + pooling. One block per (i, b).
// ---------------------------------------------------------------------------
__launch_bounds__(256)
__global__ void attn_pool(const float* __restrict__ Lbuf, const u16* __restrict__ Hbuf,
                          float* __restrict__ pooled, int level, int m)
{
    const int blk = blockIdx.x;            // i*1024 + b
    const int i = blk >> 10, bb = blk & 1023;
    const int tid = threadIdx.x;
    __shared__ float raw[64];
    __shared__ float wsm[64];
    if (tid < m) raw[tid] = Lbuf[((long)(i * m + tid)) * 1024 + bb];
    __syncthreads();
    if (tid == 0) {
        float mx = -1e30f;
        for (int d = 0; d < m; d++) mx = fmaxf(mx, raw[d]);
        float s = 0.f;
        for (int d = 0; d < m; d++) { float e = expf(raw[d] - mx); wsm[d] = e; s += e; }
        float inv = 1.f / s;
        for (int d = 0; d < m; d++) wsm[d] *= inv;
    }
    __syncthreads();
    float accv = 0.f;
    const int h = tid;
    int cum = 0;
    for (int lp = 0; lp < level; lp++) {
        int sz = 1 << (level - lp);
        int base = 64 - (64 >> lp);
        for (int q = 0; q < sz; q++) {
            long row = (long)(base + i * sz + q) * 1024 + bb;
            accv = fmaf(wsm[cum + q], b2f(Hbuf[row * 256 + h]), accv);
        }
        cum += sz;
    }
    pooled[(long)blk * 256 + h] = accv;
}

// ---------------------------------------------------------------------------
// Output heads. One block per batch b.
// ---------------------------------------------------------------------------
__launch_bounds__(256)
__global__ void heads_kernel(const u16* __restrict__ Hbuf,
                             const float* __restrict__ W_c1, const float* __restrict__ b_c1,
                             const float* __restrict__ W_c2, const float* __restrict__ b_c2,
                             const float* __restrict__ W_c3, const float* __restrict__ b_c3,
                             const float* __restrict__ W_d1, const float* __restrict__ b_d1,
                             const float* __restrict__ W_d2, const float* __restrict__ b_d2,
                             const float* __restrict__ W_d3, const float* __restrict__ b_d3,
                             float* __restrict__ out)
{
    const int bb = blockIdx.x, tid = threadIdx.x;
    __shared__ float root[256];
    __shared__ float t1[128];
    __shared__ float t2[128];
    __shared__ float red[256];
    root[tid] = b2f(Hbuf[((long)62 * 1024 + bb) * 256 + tid]);
    __syncthreads();
    for (int head = 0; head < 2; head++) {
        const float* w1  = head ? W_d1 : W_c1;
        const float* bi1 = head ? b_d1 : b_c1;
        const float* w2  = head ? W_d2 : W_c2;
        const float* bi2 = head ? b_d2 : b_c2;
        const float* w3  = head ? W_d3 : W_c3;
        const float* bi3 = head ? b_d3 : b_c3;
        if (tid < 128) {
            float s = bi1[tid];
            for (int k = 0; k < 256; k++) s = fmaf(root[k], w1[k * 128 + tid], s);
            t1[tid] = fmaxf(s, 0.f);
        }
        __syncthreads();
        if (tid < 128) {
            float s = bi2[tid];
            for (int k = 0; k < 128; k++) s = fmaf(t1[k], w2[k * 128 + tid], s);
            t2[tid] = fmaxf(s, 0.f);
        }
        __syncthreads();
        red[tid] = (tid < 128) ? t2[tid] * w3[tid] : 0.f;
        __syncthreads();
        for (int s = 128; s; s >>= 1) { if (tid < s) red[tid] += red[tid + s]; __syncthreads(); }
        if (tid == 0) out[head * 1024 + bb] = sigf(red[0] + bi3[0]);
        __syncthreads();
    }
}

// ---------------------------------------------------------------------------
extern "C" void kernel_launch(void* const* d_in, const int* in_sizes, int n_in,
                              void* d_out, int out_size, void* d_ws, size_t ws_size,
                              hipStream_t stream)
{
    (void)in_sizes; (void)n_in; (void)out_size;
    const float* op       = (const float*)d_in[0];
    const float* feat     = (const float*)d_in[1];
    const float* cond1    = (const float*)d_in[2];
    const float* cond2    = (const float*)d_in[3];
    const float* bitmap   = (const float*)d_in[4];
    const float* has_cond = (const float*)d_in[5];
    const float* W_op     = (const float*)d_in[6];
    const float* b_op     = (const float*)d_in[7];
    const float* W_feat   = (const float*)d_in[8];
    const float* b_feat   = (const float*)d_in[9];
    const float* W_pred   = (const float*)d_in[10];
    const float* b_pred   = (const float*)d_in[11];
    const float* W_bm     = (const float*)d_in[12];
    const float* b_bm     = (const float*)d_in[13];
    const float* W_ih     = (const float*)d_in[14];
    const float* b_ih     = (const float*)d_in[15];
    const float* W_hh     = (const float*)d_in[16];
    const float* b_hh     = (const float*)d_in[17];
    const float* W_wh     = (const float*)d_in[18];
    const float* W_ext    = (const float*)d_in[19];
    const float* W_a      = (const float*)d_in[20];
    const float* W_ht     = (const float*)d_in[21];
    const float* b_ht     = (const float*)d_in[22];
    const float* W_c1     = (const float*)d_in[23];
    const float* b_c1     = (const float*)d_in[24];
    const float* W_c2     = (const float*)d_in[25];
    const float* b_c2     = (const float*)d_in[26];
    const float* W_c3     = (const float*)d_in[27];
    const float* b_c3     = (const float*)d_in[28];
    const float* W_d1     = (const float*)d_in[29];
    const float* b_d1     = (const float*)d_in[30];
    const float* W_d2     = (const float*)d_in[31];
    const float* b_d2     = (const float*)d_in[32];
    const float* W_d3     = (const float*)d_in[33];
    const float* b_d3     = (const float*)d_in[34];
    float* out = (float*)d_out;

    // workspace layout, node-major rows: row = node_global*1024 + b
    char* p = (char*)d_ws;
    auto alloc = [&](size_t bytes) -> char* {
        char* r = p; p += (bytes + 255) & ~(size_t)255; return r;
    };
    u16*   xall    = (u16*)  alloc((size_t)64512 * 640 * 2);   // bf16 x, all 63 nodes
    u16*   xg      = (u16*)  alloc((size_t)64512 * 1024 * 2);  // x @ W_ih^T + biases
    float* xextall = (float*)alloc((size_t)64512 * 64 * 4);    // x @ W_ext
    u16*   Hbuf    = (u16*)  alloc((size_t)64512 * 256 * 2);   // hiddens (bf16)
    float* Cbuf    = (float*)alloc((size_t)64512 * 256 * 4);   // cells (f32)
    float* Ebuf    = (float*)alloc((size_t)62 * 1024 * 64 * 4);// H @ W_wh
    float* pooled  = (float*)alloc((size_t)16384 * 256 * 4);
    u16*   h0      = (u16*)  alloc((size_t)16384 * 256 * 2);
    float* Lbuf    = (float*)alloc((size_t)65536 * 4);
    u16*   Wt_op   = (u16*)  alloc((size_t)128 * 32 * 2);
    u16*   Wt_feat = (u16*)  alloc((size_t)128 * 64 * 2);
    u16*   Wt_pred = (u16*)  alloc((size_t)128 * 256 * 2);
    u16*   Wt_bm   = (u16*)  alloc((size_t)128 * 1024 * 2);
    u16*   Wt_ih   = (u16*)  alloc((size_t)1024 * 640 * 2);
    u16*   Wt_hh   = (u16*)  alloc((size_t)1024 * 256 * 2);
    u16*   Wt_wh   = (u16*)  alloc((size_t)64 * 256 * 2);
    u16*   Wt_ext  = (u16*)  alloc((size_t)64 * 640 * 2);
    u16*   Wt_ht   = (u16*)  alloc((size_t)256 * 256 * 2);
    float* bsum    = (float*)alloc((size_t)1024 * 4);
    if (ws_size < (size_t)(p - (char*)d_ws)) return;

    // ---- weight prep
    prep_w<<<16,  256, 0, stream>>>(W_op,   Wt_op,   32,   128, 32);
    prep_w<<<32,  256, 0, stream>>>(W_feat, Wt_feat, 64,   128, 64);
    prep_w<<<128, 256, 0, stream>>>(W_pred, Wt_pred, 256,  128, 256);
    prep_w<<<512, 256, 0, stream>>>(W_bm,   Wt_bm,   1000, 128, 1024);
    prep_w<<<64,  256, 0, stream>>>(W_wh,   Wt_wh,   256,  64,  256);
    prep_w<<<160, 256, 0, stream>>>(W_ext,  Wt_ext,  640,  64,  640);
    prep_w<<<256, 256, 0, stream>>>(W_ht,   Wt_ht,   256,  256, 256);
    prep_cvt<<<2560, 256, 0, stream>>>(W_ih, Wt_ih, 1024 * 640);
    prep_cvt<<<1024, 256, 0, stream>>>(W_hh, Wt_hh, 1024 * 256);
    prep_bias<<<4, 256, 0, stream>>>(b_ih, b_hh, bsum);

    // ---- x projections for ALL 63 nodes (M = 64512 = 504*128)
    gemm_bf16<true,128><<<dim3(504,1), 256, 0, stream>>>(op,     Wt_op,   (void*)(xall + 0),   b_op,   nullptr,  32,   32,   32,   640, 1, 0, 1);
    gemm_bf16<true,128><<<dim3(504,1), 256, 0, stream>>>(feat,   Wt_feat, (void*)(xall + 128), b_feat, nullptr,  64,   64,   64,   640, 1, 0, 1);
    gemm_bf16<true,128><<<dim3(504,1), 256, 0, stream>>>(cond1,  Wt_pred, (void*)(xall + 256), b_pred, nullptr,  256,  256,  256,  640, 1, 0, 1);
    gemm_bf16<true,128><<<dim3(504,1), 256, 0, stream>>>(cond2,  Wt_pred, (void*)(xall + 384), b_pred, nullptr,  256,  256,  256,  640, 1, 0, 1);
    gemm_bf16<true,128><<<dim3(504,1), 256, 0, stream>>>(bitmap, Wt_bm,   (void*)(xall + 512), b_bm,   has_cond, 1000, 1024, 1000, 640, 1, 0, 1);
    // xext for all nodes
    gemm_bf16<false,64><<<dim3(504,1), 256, 0, stream>>>(xall, Wt_ext, (void*)xextall, nullptr, nullptr, 640, 640, 640, 64, 0, 0, 0);
    // x-gates for all nodes: xg = xall @ W_ih^T + (b_ih + b_hh)
    gemm_bf16<false,256><<<dim3(504,4), 256, 0, stream>>>(xall, Wt_ih, (void*)xg, bsum, nullptr, 640, 640, 640, 1024, 0, 0, 1);

    for (int l = 0; l < 6; l++) {
        const int n   = 32 >> l;
        const int off = 64 - (64 >> l);     // OFFSETS[l] = global node base
        const int M   = n * 1024;
        const int m   = (2 << l) - 2;

        if (l > 0) {
            int rows = off * 1024;
            attn_logits<<<rows / 4, 256, 0, stream>>>(Ebuf, xextall, W_a, Lbuf, l, rows, m, off);
            attn_pool<<<M, 256, 0, stream>>>(Lbuf, Hbuf, pooled, l, m);
            gemm_bf16<true,128><<<dim3(M/128, 2), 256, 0, stream>>>(pooled, Wt_ht, (void*)h0, b_ht, nullptr, 256, 256, 256, 256, 0, 1, 1);
            const int offPrev = 64 - (64 >> (l - 1));
            gates_h<<<dim3(M/128, 4), 256, 0, stream>>>(h0, Wt_hh, xg, Cbuf, Hbuf, Cbuf, off, offPrev);
        } else {
            lstm0<<<8192, 256, 0, stream>>>(xg, Hbuf, Cbuf);
        }

        if (l < 5) {
            gemm_bf16<false,64><<<dim3(M/128, 1), 256, 0, stream>>>(Hbuf + (size_t)off * 1024 * 256, Wt_wh,
                                                                    (void*)(Ebuf + (size_t)off * 1024 * 64),
                                                                    nullptr, nullptr, 256, 256, 256, 64, 0, 0, 0);
        }
    }

    heads_kernel<<<1024, 256, 0, stream>>>(Hbuf, W_c1, b_c1, W_c2, b_c2, W_c3, b_c3,
                                           W_d1, b_d1, W_d2, b_d2, W_d3, b_d3, out);
}